// Round 13
// baseline (160.603 us; speedup 1.0000x reference)
//
#include <hip/hip_runtime.h>
#include <stdint.h>

// ExpertLoRA: N=8192, Z=1024, H=2048, W=64, R=8, SCALE=1.0
// Round 13: champion structure + bf16 weights (converted per-launch into
// d_ws). LDS 80->40 KB -> 4 blocks/CU, all 576 blocks co-resident.
// Per-chunk staging = 1 stage16/wave (waves 0-3: b1, waves 4-7: a2).
// Counted-vmcnt: prologue WAITVM(0) (reorder-proof), uniform WAITVM(2).
// Fallback to f32 champion if ws_size too small.

constexpr int Zd = 1024;
constexpr int Hd = 2048;
constexpr int Rr = 8;
constexpr int Wn = 64;
constexpr int TB = 16;           // tokens per block
constexpr int TW = 2;            // tokens per wave
constexpr int NT = 512;          // threads per block (8 waves)
constexpr int HC = 256;          // phase-2 H chunk (elements)
constexpr int NCHUNK = Hd / HC;  // 8
constexpr float kScale = 1.0f;

// ws layout: ints [0]=n_blocks, [16..16+N)=order, int4 btab at 16+N;
// bf16 weights at byte 65536: a1bf(1M) b1bf(2M) a2bf(2M) b2bf(1M).
constexpr size_t WOFF = 65536;
constexpr size_t WS_NEEDED = WOFF + 6 * 1024 * 1024;

__global__ __launch_bounds__(1024) void bucket_kernel(
    const int* __restrict__ a_idx, int N, int* __restrict__ ws)
{
    __shared__ int hist[Wn];
    __shared__ int cursor[Wn];
    const int t = threadIdx.x;
    if (t < Wn) hist[t] = 0;
    __syncthreads();
    for (int i = t; i < N / 4; i += 1024) {
        const int4 v = ((const int4*)a_idx)[i];
        atomicAdd(&hist[v.x], 1); atomicAdd(&hist[v.y], 1);
        atomicAdd(&hist[v.z], 1); atomicAdd(&hist[v.w], 1);
    }
    for (int i = (N & ~3) + t; i < N; i += 1024) atomicAdd(&hist[a_idx[i]], 1);
    __syncthreads();

    if (t < Wn) {                       // wave 0 does both prefix scans
        const int c = hist[t];
        int scan = c;
#pragma unroll
        for (int off = 1; off < 64; off <<= 1) {
            const int v = __shfl_up(scan, off, 64);
            if (t >= off) scan += v;
        }
        const int base = scan - c;

        const int nb_e = (c + TB - 1) / TB;
        int bs = nb_e;
#pragma unroll
        for (int off = 1; off < 64; off <<= 1) {
            const int v = __shfl_up(bs, off, 64);
            if (t >= off) bs += v;
        }
        const int bstart = bs - nb_e;
        if (t == Wn - 1) ws[0] = bs;
        cursor[t] = base;

        int4* btab = (int4*)(ws + 16 + N);
        for (int s = 0, k = 0; s < c; s += TB, ++k)
            btab[bstart + k] = make_int4(t, base + s, min(TB, c - s), 0);
    }
    __syncthreads();
    int* order = ws + 16;
    for (int i = t; i < N / 4; i += 1024) {
        const int4 v = ((const int4*)a_idx)[i];
        order[atomicAdd(&cursor[v.x], 1)] = 4 * i + 0;
        order[atomicAdd(&cursor[v.y], 1)] = 4 * i + 1;
        order[atomicAdd(&cursor[v.z], 1)] = 4 * i + 2;
        order[atomicAdd(&cursor[v.w], 1)] = 4 * i + 3;
    }
    for (int i = (N & ~3) + t; i < N; i += 1024)
        order[atomicAdd(&cursor[a_idx[i]], 1)] = i;
}

__device__ __forceinline__ unsigned short f2bf(float f) {   // RNE
    unsigned u = __float_as_uint(f);
    u += 0x7FFFu + ((u >> 16) & 1u);
    return (unsigned short)(u >> 16);
}

// Convert all 4 weight tensors (3,145,728 f32) to bf16 in ws.
// 8-elem chunks: a1 [0,65536) b1 [65536,196608) a2 [196608,327680) b2 rest.
__global__ __launch_bounds__(256) void convert_bf16(
    const float* __restrict__ a1, const float* __restrict__ b1,
    const float* __restrict__ a2, const float* __restrict__ b2,
    unsigned short* __restrict__ wb)
{
    const int idx = blockIdx.x * 256 + threadIdx.x;
    const float* src; size_t so; unsigned short* dst;
    if (idx < 65536)       { src = a1; so = (size_t)idx * 8;            dst = wb + so; }
    else if (idx < 196608) { src = b1; so = (size_t)(idx - 65536) * 8;  dst = wb + 524288 + so; }
    else if (idx < 327680) { src = a2; so = (size_t)(idx - 196608) * 8; dst = wb + 1572864 + so; }
    else                   { src = b2; so = (size_t)(idx - 327680) * 8; dst = wb + 2621440 + so; }
    const float4 v0 = *(const float4*)(src + so);
    const float4 v1 = *(const float4*)(src + so + 4);
    ushort r[8] = { f2bf(v0.x), f2bf(v0.y), f2bf(v0.z), f2bf(v0.w),
                    f2bf(v1.x), f2bf(v1.y), f2bf(v1.z), f2bf(v1.w) };
    *(uint4*)dst = *(const uint4*)r;
}

__device__ __forceinline__ float wave_allreduce(float v) {
#pragma unroll
    for (int off = 1; off < 64; off <<= 1)
        v += __shfl_xor(v, off, 64);
    return v;
}

__device__ __forceinline__ float dot8a(const float* t, const float* w) {
    return fmaf(t[0], w[0], fmaf(t[1], w[1], fmaf(t[2], w[2], fmaf(t[3], w[3],
           fmaf(t[4], w[4], fmaf(t[5], w[5], fmaf(t[6], w[6], t[7] * w[7])))))));
}

__device__ __forceinline__ float dot8(const float* t, float4 w0, float4 w1) {
    return fmaf(t[0], w0.x, fmaf(t[1], w0.y, fmaf(t[2], w0.z, fmaf(t[3], w0.w,
           fmaf(t[4], w1.x, fmaf(t[5], w1.y, fmaf(t[6], w1.z, t[7] * w1.w)))))));
}

__device__ __forceinline__ float silu(float x) {
    return x * __builtin_amdgcn_rcpf(1.f + __expf(-x));
}

// XOR swizzle: involution on byte offsets (bits 4-6 ^= bits 7-9).
__device__ __forceinline__ int swz(int o) {
    return o ^ (((o >> 7) & 7) << 4);
}

// bf16x8 (uint4) -> 8 f32
__device__ __forceinline__ void unpack8(const uint4 raw, float* w) {
    w[0] = __uint_as_float(raw.x << 16); w[1] = __uint_as_float(raw.x & 0xFFFF0000u);
    w[2] = __uint_as_float(raw.y << 16); w[3] = __uint_as_float(raw.y & 0xFFFF0000u);
    w[4] = __uint_as_float(raw.z << 16); w[5] = __uint_as_float(raw.z & 0xFFFF0000u);
    w[6] = __uint_as_float(raw.w << 16); w[7] = __uint_as_float(raw.w & 0xFFFF0000u);
}

// async global -> LDS, 16 B per lane. LDS dest is wave-uniform base
// (HW adds lane*16); global src is per-lane.
__device__ __forceinline__ void stage16(const void* g, void* l) {
    __builtin_amdgcn_global_load_lds(
        (const __attribute__((address_space(1))) uint32_t*)g,
        (__attribute__((address_space(3))) uint32_t*)l, 16, 0, 0);
}

#define WAITVM(N) asm volatile("s_waitcnt vmcnt(" #N ")" ::: "memory")
#define SYNC()    asm volatile("s_waitcnt lgkmcnt(0)\ns_barrier" ::: "memory")

// ===================== bf16-weight main kernel (40 KB LDS) ================
__global__ __launch_bounds__(NT, 6) void lora_main_bf16(
    const float* __restrict__ z,
    const float* __restrict__ h_pre,
    const float* __restrict__ out_pre,
    float* __restrict__ out,
    const int* __restrict__ ws, int N,
    const char* __restrict__ wb)        // bf16 weight base
{
    // pool bytes: [0,16K) a1bf then b2bf; [16K,28K) s_b1 x3; [28K,40K) s_a2 x3
    __shared__ float4 s_pool[2560];     // 40 KB
    char* pool = (char*)s_pool;

    const int cpx = gridDim.x >> 3;
    const int lb  = (blockIdx.x & 7) * cpx + (blockIdx.x >> 3);
    if (lb >= ws[0]) return;

    const int4 desc = ((const int4*)(ws + 16 + N))[lb];
    const int e = desc.x, start = desc.y, cnt = desc.z;
    const int* order = ws + 16;

    const int t    = threadIdx.x;
    const int wave = t >> 6;
    const int lane = t & 63;

    bool val[TW];
    int  tok[TW];
#pragma unroll
    for (int k = 0; k < TW; ++k) {
        const int idx = wave * TW + k;
        val[k] = (idx < cnt);
        tok[k] = order[start + (val[k] ? idx : 0)];
    }

    const char* a1e = wb + (size_t)e * 16384;              // [R][Z] bf16
    const char* b1e = wb + 1048576 + (size_t)e * 32768;    // [H][R] bf16
    const char* a2e = wb + 3145728 + (size_t)e * 32768;    // [R][H] bf16
    const char* b2e = wb + 5242880 + (size_t)e * 16384;    // [Z][R] bf16

    const int wp = wave - 4;            // a2-staging wave index (waves 4-7)

    // ---- prologue: a1bf (2 ops) linear; chunk0 (1 op/wave); hv0 ----
#pragma unroll
    for (int i = 0; i < 2; ++i)
        stage16(a1e + (i * NT + t) * 16, pool + (i * NT + wave * 64) * 16);
    if (wave < 4)
        stage16(b1e + swz(t * 16), pool + 16384 + wave * 1024);
    else
        stage16(a2e + (2 * wp + (lane >> 5)) * (Hd * 2) + (lane & 31) * 16,
                pool + 28672 + wp * 1024);
    float4 hv[2][TW];
#pragma unroll
    for (int k = 0; k < TW; ++k)
        hv[0][k] = *(const float4*)(h_pre + (size_t)tok[k] * Hd + 4 * lane);

    WAITVM(0);     // full drain: robust to any compiler reorder of prologue
    SYNC();

    // ---------- Phase 1: t1[k][r] = sum_d z[tok,d]*a1[e,r,d] (LDS bf16) ----
    float p[TW][Rr];
#pragma unroll
    for (int k = 0; k < TW; ++k)
#pragma unroll
        for (int r = 0; r < Rr; ++r) p[k][r] = 0.f;

#pragma unroll
    for (int i = 0; i < 2; ++i) {                   // lane owns 8 elems/iter
        const int c8 = lane + i * 64;               // 16B unit in 2KB row
        float4 za[TW], zb[TW];
#pragma unroll
        for (int k = 0; k < TW; ++k) {
            za[k] = *(const float4*)(z + (size_t)tok[k] * Zd + 8 * c8);
            zb[k] = *(const float4*)(z + (size_t)tok[k] * Zd + 8 * c8 + 4);
        }
#pragma unroll
        for (int r = 0; r < Rr; ++r) {
            float wv[8];
            unpack8(*(const uint4*)(pool + r * 2048 + c8 * 16), wv);
#pragma unroll
            for (int k = 0; k < TW; ++k) {
                float acc = p[k][r];
                acc = fmaf(za[k].x, wv[0], acc); acc = fmaf(za[k].y, wv[1], acc);
                acc = fmaf(za[k].z, wv[2], acc); acc = fmaf(za[k].w, wv[3], acc);
                acc = fmaf(zb[k].x, wv[4], acc); acc = fmaf(zb[k].y, wv[5], acc);
                acc = fmaf(zb[k].z, wv[6], acc); acc = fmaf(zb[k].w, wv[7], acc);
                p[k][r] = acc;
            }
        }
    }
    float t1[TW][Rr];
#pragma unroll
    for (int k = 0; k < TW; ++k)
#pragma unroll
        for (int r = 0; r < Rr; ++r) t1[k][r] = wave_allreduce(p[k][r]);

    SYNC();        // all waves done reading a1; region free for b2

    // b2bf (2 ops, swizzled src) into a1 region; chunk1 (1 op/wave)
#pragma unroll
    for (int i = 0; i < 2; ++i)
        stage16(b2e + swz((i * NT + t) * 16), pool + (i * NT + wave * 64) * 16);
    if (wave < 4)
        stage16(b1e + 4096 + swz(t * 16), pool + 16384 + 4096 + wave * 1024);
    else
        stage16(a2e + (2 * wp + (lane >> 5)) * (Hd * 2) + 512 + (lane & 31) * 16,
                pool + 28672 + 4096 + wp * 1024);

    // ---------- Phase 2: 8 chunks, 3-buffer counted-vmcnt pipeline ----------
    float q[TW][Rr];
#pragma unroll
    for (int k = 0; k < TW; ++k)
#pragma unroll
        for (int r = 0; r < Rr; ++r) q[k][r] = 0.f;

#pragma unroll
    for (int kc = 0; kc < NCHUNK; ++kc) {
        // queue before wait (steady): c(kc), hv(kc)[2], c(kc+1) -> WAITVM(2)
        // guarantees own c(kc) landed under any hv/stage issue reorder.
        WAITVM(2);
        SYNC();

        if (kc + 1 < NCHUNK) {          // hv prefetch FIRST (stays older)
            const int cc = (kc + 1) * 64 + lane;
#pragma unroll
            for (int k = 0; k < TW; ++k)
                hv[(kc + 1) & 1][k] =
                    *(const float4*)(h_pre + (size_t)tok[k] * Hd + 4 * cc);
        }
        if (kc + 2 < NCHUNK) {          // stage chunk kc+2 (1 op/wave)
            const int nb = (kc + 2) % 3;
            if (wave < 4)
                stage16(b1e + (size_t)(kc + 2) * 4096 + swz(t * 16),
                        pool + 16384 + nb * 4096 + wave * 1024);
            else
                stage16(a2e + (2 * wp + (lane >> 5)) * (Hd * 2)
                            + (kc + 2) * 512 + (lane & 31) * 16,
                        pool + 28672 + nb * 4096 + wp * 1024);
        }

        const int cb1 = 16384 + (kc % 3) * 4096;
        const int ca2 = 28672 + (kc % 3) * 4096;

        float sv[TW][4];
#pragma unroll
        for (int j = 0; j < 4; ++j) {
            const int o0 = (4 * lane + j) * 16;     // row byte in 4KB chunk
            float wv[8];
            unpack8(*(const uint4*)(pool + cb1 + swz(o0)), wv);
#pragma unroll
            for (int k = 0; k < TW; ++k) {
                const float x = (&hv[kc & 1][k].x)[j] + dot8a(t1[k], wv) * kScale;
                sv[k][j] = silu(x);
            }
        }
#pragma unroll
        for (int r = 0; r < Rr; ++r) {
            const uint2 rw = *(const uint2*)(pool + ca2 + r * 512 + lane * 8);
            const float a0 = __uint_as_float(rw.x << 16);
            const float a1v = __uint_as_float(rw.x & 0xFFFF0000u);
            const float a2v = __uint_as_float(rw.y << 16);
            const float a3 = __uint_as_float(rw.y & 0xFFFF0000u);
#pragma unroll
            for (int k = 0; k < TW; ++k)
                q[k][r] = fmaf(sv[k][0], a0, fmaf(sv[k][1], a1v,
                          fmaf(sv[k][2], a2v, fmaf(sv[k][3], a3, q[k][r]))));
        }
    }

    float t2[TW][Rr];
#pragma unroll
    for (int k = 0; k < TW; ++k)
#pragma unroll
        for (int r = 0; r < Rr; ++r) t2[k][r] = wave_allreduce(q[k][r]) * kScale;

    WAITVM(0);     // b2 long retired (kc<=1 waits); cheap safety
    SYNC();

    // ---------- Phase 3: out = out_pre + t2·b2  (b2bf at pool[0,16K)) ------
#pragma unroll
    for (int i = 0; i < Zd / 4 / 64; ++i) {         // 4 iters
        const int c = lane + i * 64;
        float4 ov[TW];
#pragma unroll
        for (int k = 0; k < TW; ++k)
            ov[k] = *(const float4*)(out_pre + (size_t)tok[k] * Zd + 4 * c);
        float4 res[TW];
#pragma unroll
        for (int j = 0; j < 4; ++j) {
            const int o0 = (4 * c + j) * 16;        // row byte in 16KB
            float wv[8];
            unpack8(*(const uint4*)(pool + swz(o0)), wv);
#pragma unroll
            for (int k = 0; k < TW; ++k)
                (&res[k].x)[j] = (&ov[k].x)[j] + dot8a(t2[k], wv);
        }
#pragma unroll
        for (int k = 0; k < TW; ++k)
            if (val[k]) *(float4*)(out + (size_t)tok[k] * Zd + 4 * c) = res[k];
    }
}

// ===================== f32 champion fallback (80 KB LDS) ==================
__global__ __launch_bounds__(NT, 4) void lora_main_f32(
    const float* __restrict__ z, const float* __restrict__ h_pre,
    const float* __restrict__ out_pre,
    const float* __restrict__ a1, const float* __restrict__ b1,
    const float* __restrict__ a2, const float* __restrict__ b2,
    float* __restrict__ out, const int* __restrict__ ws, int N)
{
    __shared__ float s_a1[Rr * Zd];
    __shared__ float s_b1[3][HC * Rr];
    __shared__ float s_a2[3][Rr * HC];

    const int cpx = gridDim.x >> 3;
    const int lb  = (blockIdx.x & 7) * cpx + (blockIdx.x >> 3);
    if (lb >= ws[0]) return;

    const int4 desc = ((const int4*)(ws + 16 + N))[lb];
    const int e = desc.x, start = desc.y, cnt = desc.z;
    const int* order = ws + 16;
    const int t = threadIdx.x, wave = t >> 6, lane = t & 63;

    bool val[TW]; int tok[TW];
#pragma unroll
    for (int k = 0; k < TW; ++k) {
        const int idx = wave * TW + k;
        val[k] = (idx < cnt);
        tok[k] = order[start + (val[k] ? idx : 0)];
    }
    const char*  a1e = (const char*)(a1 + (size_t)e * (Rr * Zd));
    const char*  b1e = (const char*)(b1 + (size_t)e * (Hd * Rr));
    const float* a2e = a2 + (size_t)e * (Rr * Hd);
    const char*  b2e = (const char*)(b2 + (size_t)e * (Zd * Rr));

#pragma unroll
    for (int i = 0; i < 4; ++i) {
        const int o = (i * NT + t) * 16;
        stage16(a1e + o, (char*)s_a1 + (i * NT + wave * 64) * 16);
    }
#pragma unroll
    for (int c0 = 0; c0 < 2; ++c0) {
        stage16(b1e + (size_t)(c0 * HC) * Rr * 4 + swz(t * 16),
                (char*)s_b1[c0] + wave * 1024);
        stage16(a2e + wave * Hd + c0 * HC + lane * 4,
                (char*)s_a2[c0] + wave * 1024);
    }
    WAITVM(4); SYNC();

    float p[TW][Rr];
#pragma unroll
    for (int k = 0; k < TW; ++k)
#pragma unroll
        for (int r = 0; r < Rr; ++r) p[k][r] = 0.f;
#pragma unroll
    for (int i = 0; i < 4; ++i) {
        const int c = lane + i * 64;
        float4 zv[TW];
#pragma unroll
        for (int k = 0; k < TW; ++k)
            zv[k] = *(const float4*)(z + (size_t)tok[k] * Zd + 4 * c);
#pragma unroll
        for (int r = 0; r < Rr; ++r) {
            const float4 w = *(const float4*)(s_a1 + r * Zd + 4 * c);
#pragma unroll
            for (int k = 0; k < TW; ++k)
                p[k][r] = fmaf(zv[k].x, w.x, fmaf(zv[k].y, w.y,
                          fmaf(zv[k].z, w.z, fmaf(zv[k].w, w.w, p[k][r]))));
        }
    }
    float t1[TW][Rr];
#pragma unroll
    for (int k = 0; k < TW; ++k)
#pragma unroll
        for (int r = 0; r < Rr; ++r) t1[k][r] = wave_allreduce(p[k][r]);
    SYNC();
#pragma unroll
    for (int i = 0; i < 4; ++i) {
        const int o = (i * NT + t) * 16;
        stage16(b2e + swz(o), (char*)s_a1 + (i * NT + wave * 64) * 16);
    }
    float q[TW][Rr];
#pragma unroll
    for (int k = 0; k < TW; ++k)
#pragma unroll
        for (int r = 0; r < Rr; ++r) q[k][r] = 0.f;
#pragma unroll
    for (int kc = 0; kc < NCHUNK; ++kc) {
        if (kc < 2)      { WAITVM(6); }
        else if (kc < 7) { WAITVM(2); }
        else             { WAITVM(0); }
        SYNC();
        if (kc + 2 < NCHUNK) {
            const int nb = (kc + 2) % 3;
            const int hb = (kc + 2) * HC;
            stage16(b1e + (size_t)hb * Rr * 4 + swz(t * 16),
                    (char*)s_b1[nb] + wave * 1024);
            stage16(a2e + wave * Hd + hb + lane * 4,
                    (char*)s_a2[nb] + wave * 1024);
        }
        const int cur = kc % 3;
        const int cc = kc * 64 + lane;
        float4 hv[TW];
#pragma unroll
        for (int k = 0; k < TW; ++k)
            hv[k] = *(const float4*)(h_pre + (size_t)tok[k] * Hd + 4 * cc);
        float sv[TW][4];
#pragma unroll
        for (int j = 0; j < 4; ++j) {
            const int o0 = lane * 128 + j * 32;
            const float4 w0 = *(const float4*)((const char*)s_b1[cur] + swz(o0));
            const float4 w1 = *(const float4*)((const char*)s_b1[cur] + swz(o0 + 16));
#pragma unroll
            for (int k = 0; k < TW; ++k) {
                const float x = (&hv[k].x)[j] + dot8(t1[k], w0, w1) * kScale;
                sv[k][j] = silu(x);
            }
        }
#pragma unroll
        for (int r = 0; r < Rr; ++r) {
            const float4 aw = *(const float4*)(s_a2[cur] + r * HC + lane * 4);
#pragma unroll
            for (int k = 0; k < TW; ++k)
                q[k][r] = fmaf(sv[k][0], aw.x, fmaf(sv[k][1], aw.y,
                          fmaf(sv[k][2], aw.z, fmaf(sv[k][3], aw.w, q[k][r]))));
        }
    }
    float t2[TW][Rr];
#pragma unroll
    for (int k = 0; k < TW; ++k)
#pragma unroll
        for (int r = 0; r < Rr; ++r) t2[k][r] = wave_allreduce(q[k][r]) * kScale;
    WAITVM(0); SYNC();
#pragma unroll
    for (int i = 0; i < 4; ++i) {
        const int c = lane + i * 64;
        float4 ov[TW];
#pragma unroll
        for (int k = 0; k < TW; ++k)
            ov[k] = *(const float4*)(out_pre + (size_t)tok[k] * Zd + 4 * c);
        float4 res[TW];
#pragma unroll
        for (int j = 0; j < 4; ++j) {
            const int o0 = c * 128 + j * 32;
            const float4 w0 = *(const float4*)((const char*)s_a1 + swz(o0));
            const float4 w1 = *(const float4*)((const char*)s_a1 + swz(o0 + 16));
#pragma unroll
            for (int k = 0; k < TW; ++k)
                (&res[k].x)[j] = (&ov[k].x)[j] + dot8(t2[k], w0, w1);
        }
#pragma unroll
        for (int k = 0; k < TW; ++k)
            if (val[k]) *(float4*)(out + (size_t)tok[k] * Zd + 4 * c) = res[k];
    }
}

extern "C" void kernel_launch(void* const* d_in, const int* in_sizes, int n_in,
                              void* d_out, int out_size, void* d_ws, size_t ws_size,
                              hipStream_t stream) {
    const float* z       = (const float*)d_in[0];
    const int*   a_idx   = (const int*)d_in[1];
    const float* h_pre   = (const float*)d_in[2];
    const float* out_pre = (const float*)d_in[3];
    const float* a1      = (const float*)d_in[4];
    const float* b1      = (const float*)d_in[5];
    const float* a2      = (const float*)d_in[6];
    const float* b2      = (const float*)d_in[7];
    float* out = (float*)d_out;

    const int N = in_sizes[1];  // a_idx count

    bucket_kernel<<<1, 1024, 0, stream>>>(a_idx, N, (int*)d_ws);

    int nwg = N / TB + Wn;              // 576 blocks (incl. per-expert tails)
    nwg = (nwg + 7) & ~7;               // multiple of 8 for XCD swizzle

    if (ws_size >= WS_NEEDED) {
        unsigned short* wb = (unsigned short*)((char*)d_ws + WOFF);
        convert_bf16<<<1536, 256, 0, stream>>>(a1, b1, a2, b2, wb);
        lora_main_bf16<<<nwg, NT, 0, stream>>>(z, h_pre, out_pre, out,
                                               (const int*)d_ws, N,
                                               (const char*)wb);
    } else {
        lora_main_f32<<<nwg, NT, 0, stream>>>(z, h_pre, out_pre,
                                              a1, b1, a2, b2, out,
                                              (const int*)d_ws, N);
    }
}

// Round 14
// 159.233 us; speedup vs baseline: 1.0086x; 1.0086x over previous
//
#include <hip/hip_runtime.h>
#include <stdint.h>

// ExpertLoRA: N=8192, Z=1024, H=2048, W=64, R=8, SCALE=1.0
// Round 14: R13 bf16-weight design with the scratch bug fixed: all unpack/dot
// helpers pass float4 BY VALUE (champion-proven codegen; no address-taken
// local arrays -> no stack demotion -> no scratch traffic).
//  - weights converted to bf16 in d_ws each launch (deterministic)
//  - LDS 40 KB: a1bf/b2bf share [0,16K); 3x4KB b1 chunks; 3x4KB a2 chunks
//  - 1 stage16 per wave per chunk (waves 0-3: b1, waves 4-7: a2)
//  - counted-vmcnt: prologue WAITVM(0); uniform WAITVM(2) per chunk
//  - f32 champion fallback if ws too small.

constexpr int Zd = 1024;
constexpr int Hd = 2048;
constexpr int Rr = 8;
constexpr int Wn = 64;
constexpr int TB = 16;           // tokens per block
constexpr int TW = 2;            // tokens per wave
constexpr int NT = 512;          // threads per block (8 waves)
constexpr int HC = 256;          // phase-2 H chunk (elements)
constexpr int NCHUNK = Hd / HC;  // 8
constexpr float kScale = 1.0f;

constexpr size_t WOFF = 65536;
constexpr size_t WS_NEEDED = WOFF + 6 * 1024 * 1024;

__global__ __launch_bounds__(1024) void bucket_kernel(
    const int* __restrict__ a_idx, int N, int* __restrict__ ws)
{
    __shared__ int hist[Wn];
    __shared__ int cursor[Wn];
    const int t = threadIdx.x;
    if (t < Wn) hist[t] = 0;
    __syncthreads();
    for (int i = t; i < N / 4; i += 1024) {
        const int4 v = ((const int4*)a_idx)[i];
        atomicAdd(&hist[v.x], 1); atomicAdd(&hist[v.y], 1);
        atomicAdd(&hist[v.z], 1); atomicAdd(&hist[v.w], 1);
    }
    for (int i = (N & ~3) + t; i < N; i += 1024) atomicAdd(&hist[a_idx[i]], 1);
    __syncthreads();

    if (t < Wn) {
        const int c = hist[t];
        int scan = c;
#pragma unroll
        for (int off = 1; off < 64; off <<= 1) {
            const int v = __shfl_up(scan, off, 64);
            if (t >= off) scan += v;
        }
        const int base = scan - c;

        const int nb_e = (c + TB - 1) / TB;
        int bs = nb_e;
#pragma unroll
        for (int off = 1; off < 64; off <<= 1) {
            const int v = __shfl_up(bs, off, 64);
            if (t >= off) bs += v;
        }
        const int bstart = bs - nb_e;
        if (t == Wn - 1) ws[0] = bs;
        cursor[t] = base;

        int4* btab = (int4*)(ws + 16 + N);
        for (int s = 0, k = 0; s < c; s += TB, ++k)
            btab[bstart + k] = make_int4(t, base + s, min(TB, c - s), 0);
    }
    __syncthreads();
    int* order = ws + 16;
    for (int i = t; i < N / 4; i += 1024) {
        const int4 v = ((const int4*)a_idx)[i];
        order[atomicAdd(&cursor[v.x], 1)] = 4 * i + 0;
        order[atomicAdd(&cursor[v.y], 1)] = 4 * i + 1;
        order[atomicAdd(&cursor[v.z], 1)] = 4 * i + 2;
        order[atomicAdd(&cursor[v.w], 1)] = 4 * i + 3;
    }
    for (int i = (N & ~3) + t; i < N; i += 1024)
        order[atomicAdd(&cursor[a_idx[i]], 1)] = i;
}

__device__ __forceinline__ unsigned f2bf(float f) {   // RNE, low 16 bits
    unsigned u = __float_as_uint(f);
    u += 0x7FFFu + ((u >> 16) & 1u);
    return u >> 16;
}
__device__ __forceinline__ unsigned pack2(float lo, float hi) {
    return f2bf(lo) | (f2bf(hi) << 16);
}

// Convert all 4 weight tensors (3,145,728 f32) to bf16 in ws. No local
// arrays (value-only) -> no scratch.
__global__ __launch_bounds__(256) void convert_bf16(
    const float* __restrict__ a1, const float* __restrict__ b1,
    const float* __restrict__ a2, const float* __restrict__ b2,
    unsigned* __restrict__ wb)          // uint view of bf16 table
{
    const int idx = blockIdx.x * 256 + threadIdx.x;
    const float* src; size_t so; unsigned* dst;
    if (idx < 65536)       { src = a1; so = (size_t)idx * 8;            dst = wb + so / 2; }
    else if (idx < 196608) { src = b1; so = (size_t)(idx - 65536) * 8;  dst = wb + 262144 + so / 2; }
    else if (idx < 327680) { src = a2; so = (size_t)(idx - 196608) * 8; dst = wb + 786432 + so / 2; }
    else                   { src = b2; so = (size_t)(idx - 327680) * 8; dst = wb + 1310720 + so / 2; }
    const float4 v0 = *(const float4*)(src + so);
    const float4 v1 = *(const float4*)(src + so + 4);
    uint4 o;
    o.x = pack2(v0.x, v0.y); o.y = pack2(v0.z, v0.w);
    o.z = pack2(v1.x, v1.y); o.w = pack2(v1.z, v1.w);
    *(uint4*)dst = o;
}

__device__ __forceinline__ float wave_allreduce(float v) {
#pragma unroll
    for (int off = 1; off < 64; off <<= 1)
        v += __shfl_xor(v, off, 64);
    return v;
}

// bf16 pair-words -> float4 (elems 2k at low16, 2k+1 at high16)
__device__ __forceinline__ float4 unpk4(unsigned a, unsigned b) {
    return make_float4(__uint_as_float(a << 16), __uint_as_float(a & 0xFFFF0000u),
                       __uint_as_float(b << 16), __uint_as_float(b & 0xFFFF0000u));
}

__device__ __forceinline__ float dot8(const float* t, float4 w0, float4 w1) {
    return fmaf(t[0], w0.x, fmaf(t[1], w0.y, fmaf(t[2], w0.z, fmaf(t[3], w0.w,
           fmaf(t[4], w1.x, fmaf(t[5], w1.y, fmaf(t[6], w1.z, t[7] * w1.w)))))));
}

__device__ __forceinline__ float silu(float x) {
    return x * __builtin_amdgcn_rcpf(1.f + __expf(-x));
}

// XOR swizzle: involution on byte offsets (bits 4-6 ^= bits 7-9).
__device__ __forceinline__ int swz(int o) {
    return o ^ (((o >> 7) & 7) << 4);
}

__device__ __forceinline__ void stage16(const void* g, void* l) {
    __builtin_amdgcn_global_load_lds(
        (const __attribute__((address_space(1))) uint32_t*)g,
        (__attribute__((address_space(3))) uint32_t*)l, 16, 0, 0);
}

#define WAITVM(N) asm volatile("s_waitcnt vmcnt(" #N ")" ::: "memory")
#define SYNC()    asm volatile("s_waitcnt lgkmcnt(0)\ns_barrier" ::: "memory")

// ===================== bf16-weight main kernel (40 KB LDS) ================
__global__ __launch_bounds__(NT, 6) void lora_main_bf16(
    const float* __restrict__ z,
    const float* __restrict__ h_pre,
    const float* __restrict__ out_pre,
    float* __restrict__ out,
    const int* __restrict__ ws, int N,
    const char* __restrict__ wb)
{
    // pool: [0,16K) a1bf then b2bf; [16K,28K) b1 x3; [28K,40K) a2 x3
    __shared__ float4 s_pool[2560];     // 40 KB
    char* pool = (char*)s_pool;

    const int cpx = gridDim.x >> 3;
    const int lb  = (blockIdx.x & 7) * cpx + (blockIdx.x >> 3);
    if (lb >= ws[0]) return;

    const int4 desc = ((const int4*)(ws + 16 + N))[lb];
    const int e = desc.x, start = desc.y, cnt = desc.z;
    const int* order = ws + 16;

    const int t    = threadIdx.x;
    const int wave = t >> 6;
    const int lane = t & 63;

    bool val[TW];
    int  tok[TW];
#pragma unroll
    for (int k = 0; k < TW; ++k) {
        const int idx = wave * TW + k;
        val[k] = (idx < cnt);
        tok[k] = order[start + (val[k] ? idx : 0)];
    }

    const char* a1e = wb + (size_t)e * 16384;              // [R][Z] bf16
    const char* b1e = wb + 1048576 + (size_t)e * 32768;    // [H][R] bf16
    const char* a2e = wb + 3145728 + (size_t)e * 32768;    // [R][H] bf16
    const char* b2e = wb + 5242880 + (size_t)e * 16384;    // [Z][R] bf16

    const int wp = wave - 4;            // a2-staging wave index (waves 4-7)

    // ---- prologue: a1bf (2 ops) linear; chunk0 (1 op/wave); hv0 ----
#pragma unroll
    for (int i = 0; i < 2; ++i)
        stage16(a1e + (i * NT + t) * 16, pool + (i * NT + wave * 64) * 16);
    if (wave < 4)
        stage16(b1e + swz(t * 16), pool + 16384 + wave * 1024);
    else
        stage16(a2e + (2 * wp + (lane >> 5)) * (Hd * 2) + (lane & 31) * 16,
                pool + 28672 + wp * 1024);
    float4 hv[2][TW];
#pragma unroll
    for (int k = 0; k < TW; ++k)
        hv[0][k] = *(const float4*)(h_pre + (size_t)tok[k] * Hd + 4 * lane);

    WAITVM(0);     // full drain: robust to any compiler reorder of prologue
    SYNC();

    // ---------- Phase 1: t1[k][r] = sum_d z[tok,d]*a1[e,r,d] (LDS bf16) ----
    float p[TW][Rr];
#pragma unroll
    for (int k = 0; k < TW; ++k)
#pragma unroll
        for (int r = 0; r < Rr; ++r) p[k][r] = 0.f;

#pragma unroll
    for (int i = 0; i < 2; ++i) {                   // lane owns 8 elems/iter
        const int c8 = lane + i * 64;               // 16B unit in 2KB row
        float4 za[TW], zb[TW];
#pragma unroll
        for (int k = 0; k < TW; ++k) {
            za[k] = *(const float4*)(z + (size_t)tok[k] * Zd + 8 * c8);
            zb[k] = *(const float4*)(z + (size_t)tok[k] * Zd + 8 * c8 + 4);
        }
#pragma unroll
        for (int r = 0; r < Rr; ++r) {
            const uint4 raw = *(const uint4*)(pool + r * 2048 + c8 * 16);
            const float4 w0 = unpk4(raw.x, raw.y);
            const float4 w1 = unpk4(raw.z, raw.w);
#pragma unroll
            for (int k = 0; k < TW; ++k) {
                float acc = p[k][r];
                acc = fmaf(za[k].x, w0.x, acc); acc = fmaf(za[k].y, w0.y, acc);
                acc = fmaf(za[k].z, w0.z, acc); acc = fmaf(za[k].w, w0.w, acc);
                acc = fmaf(zb[k].x, w1.x, acc); acc = fmaf(zb[k].y, w1.y, acc);
                acc = fmaf(zb[k].z, w1.z, acc); acc = fmaf(zb[k].w, w1.w, acc);
                p[k][r] = acc;
            }
        }
    }
    float t1[TW][Rr];
#pragma unroll
    for (int k = 0; k < TW; ++k)
#pragma unroll
        for (int r = 0; r < Rr; ++r) t1[k][r] = wave_allreduce(p[k][r]);

    SYNC();        // all waves done reading a1; region free for b2

    // b2bf (2 ops, swizzled src) into a1 region; chunk1 (1 op/wave)
#pragma unroll
    for (int i = 0; i < 2; ++i)
        stage16(b2e + swz((i * NT + t) * 16), pool + (i * NT + wave * 64) * 16);
    if (wave < 4)
        stage16(b1e + 4096 + swz(t * 16), pool + 16384 + 4096 + wave * 1024);
    else
        stage16(a2e + (2 * wp + (lane >> 5)) * (Hd * 2) + 512 + (lane & 31) * 16,
                pool + 28672 + 4096 + wp * 1024);

    // ---------- Phase 2: 8 chunks, 3-buffer counted-vmcnt pipeline ----------
    float q[TW][Rr];
#pragma unroll
    for (int k = 0; k < TW; ++k)
#pragma unroll
        for (int r = 0; r < Rr; ++r) q[k][r] = 0.f;

#pragma unroll
    for (int kc = 0; kc < NCHUNK; ++kc) {
        // Ledger (1 stage op/wave): WAITVM(2) retires own stage(kc) at every
        // kc (verified kc=0..7 incl. b2 ops after phase 1).
        WAITVM(2);
        SYNC();

        if (kc + 1 < NCHUNK) {          // hv prefetch FIRST (stays older)
            const int cc = (kc + 1) * 64 + lane;
#pragma unroll
            for (int k = 0; k < TW; ++k)
                hv[(kc + 1) & 1][k] =
                    *(const float4*)(h_pre + (size_t)tok[k] * Hd + 4 * cc);
        }
        if (kc + 2 < NCHUNK) {          // stage chunk kc+2 (1 op/wave)
            const int nb = (kc + 2) % 3;
            if (wave < 4)
                stage16(b1e + (size_t)(kc + 2) * 4096 + swz(t * 16),
                        pool + 16384 + nb * 4096 + wave * 1024);
            else
                stage16(a2e + (2 * wp + (lane >> 5)) * (Hd * 2)
                            + (kc + 2) * 512 + (lane & 31) * 16,
                        pool + 28672 + nb * 4096 + wp * 1024);
        }

        const int cb1 = 16384 + (kc % 3) * 4096;
        const int ca2 = 28672 + (kc % 3) * 4096;

        float sv[TW][4];
#pragma unroll
        for (int j = 0; j < 4; ++j) {
            const int o0 = (4 * lane + j) * 16;     // row byte in 4KB chunk
            const uint4 raw = *(const uint4*)(pool + cb1 + swz(o0));
            const float4 w0 = unpk4(raw.x, raw.y);
            const float4 w1 = unpk4(raw.z, raw.w);
#pragma unroll
            for (int k = 0; k < TW; ++k) {
                const float x = (&hv[kc & 1][k].x)[j] + dot8(t1[k], w0, w1) * kScale;
                sv[k][j] = silu(x);
            }
        }
#pragma unroll
        for (int r = 0; r < Rr; ++r) {
            const uint2 rw = *(const uint2*)(pool + ca2 + r * 512 + lane * 8);
            const float4 aw = unpk4(rw.x, rw.y);
#pragma unroll
            for (int k = 0; k < TW; ++k)
                q[k][r] = fmaf(sv[k][0], aw.x, fmaf(sv[k][1], aw.y,
                          fmaf(sv[k][2], aw.z, fmaf(sv[k][3], aw.w, q[k][r]))));
        }
    }

    float t2[TW][Rr];
#pragma unroll
    for (int k = 0; k < TW; ++k)
#pragma unroll
        for (int r = 0; r < Rr; ++r) t2[k][r] = wave_allreduce(q[k][r]) * kScale;

    WAITVM(0);     // b2 long retired; cheap safety
    SYNC();

    // ---------- Phase 3: out = out_pre + t2·b2  (b2bf at pool[0,16K)) ------
#pragma unroll
    for (int i = 0; i < Zd / 4 / 64; ++i) {         // 4 iters
        const int c = lane + i * 64;
        float4 ov[TW];
#pragma unroll
        for (int k = 0; k < TW; ++k)
            ov[k] = *(const float4*)(out_pre + (size_t)tok[k] * Zd + 4 * c);
        float4 res[TW];
#pragma unroll
        for (int j = 0; j < 4; ++j) {
            const int o0 = (4 * c + j) * 16;        // row byte in 16KB
            const uint4 raw = *(const uint4*)(pool + swz(o0));
            const float4 w0 = unpk4(raw.x, raw.y);
            const float4 w1 = unpk4(raw.z, raw.w);
#pragma unroll
            for (int k = 0; k < TW; ++k)
                (&res[k].x)[j] = (&ov[k].x)[j] + dot8(t2[k], w0, w1);
        }
#pragma unroll
        for (int k = 0; k < TW; ++k)
            if (val[k]) *(float4*)(out + (size_t)tok[k] * Zd + 4 * c) = res[k];
    }
}

// ===================== f32 champion fallback (80 KB LDS) ==================
__global__ __launch_bounds__(NT, 4) void lora_main_f32(
    const float* __restrict__ z, const float* __restrict__ h_pre,
    const float* __restrict__ out_pre,
    const float* __restrict__ a1, const float* __restrict__ b1,
    const float* __restrict__ a2, const float* __restrict__ b2,
    float* __restrict__ out, const int* __restrict__ ws, int N)
{
    __shared__ float s_a1[Rr * Zd];
    __shared__ float s_b1[3][HC * Rr];
    __shared__ float s_a2[3][Rr * HC];

    const int cpx = gridDim.x >> 3;
    const int lb  = (blockIdx.x & 7) * cpx + (blockIdx.x >> 3);
    if (lb >= ws[0]) return;

    const int4 desc = ((const int4*)(ws + 16 + N))[lb];
    const int e = desc.x, start = desc.y, cnt = desc.z;
    const int* order = ws + 16;
    const int t = threadIdx.x, wave = t >> 6, lane = t & 63;

    bool val[TW]; int tok[TW];
#pragma unroll
    for (int k = 0; k < TW; ++k) {
        const int idx = wave * TW + k;
        val[k] = (idx < cnt);
        tok[k] = order[start + (val[k] ? idx : 0)];
    }
    const char*  a1e = (const char*)(a1 + (size_t)e * (Rr * Zd));
    const char*  b1e = (const char*)(b1 + (size_t)e * (Hd * Rr));
    const float* a2e = a2 + (size_t)e * (Rr * Hd);
    const char*  b2e = (const char*)(b2 + (size_t)e * (Zd * Rr));

#pragma unroll
    for (int i = 0; i < 4; ++i) {
        const int o = (i * NT + t) * 16;
        stage16(a1e + o, (char*)s_a1 + (i * NT + wave * 64) * 16);
    }
#pragma unroll
    for (int c0 = 0; c0 < 2; ++c0) {
        stage16(b1e + (size_t)(c0 * HC) * Rr * 4 + swz(t * 16),
                (char*)s_b1[c0] + wave * 1024);
        stage16(a2e + wave * Hd + c0 * HC + lane * 4,
                (char*)s_a2[c0] + wave * 1024);
    }
    WAITVM(4); SYNC();

    float p[TW][Rr];
#pragma unroll
    for (int k = 0; k < TW; ++k)
#pragma unroll
        for (int r = 0; r < Rr; ++r) p[k][r] = 0.f;
#pragma unroll
    for (int i = 0; i < 4; ++i) {
        const int c = lane + i * 64;
        float4 zv[TW];
#pragma unroll
        for (int k = 0; k < TW; ++k)
            zv[k] = *(const float4*)(z + (size_t)tok[k] * Zd + 4 * c);
#pragma unroll
        for (int r = 0; r < Rr; ++r) {
            const float4 w = *(const float4*)(s_a1 + r * Zd + 4 * c);
#pragma unroll
            for (int k = 0; k < TW; ++k)
                p[k][r] = fmaf(zv[k].x, w.x, fmaf(zv[k].y, w.y,
                          fmaf(zv[k].z, w.z, fmaf(zv[k].w, w.w, p[k][r]))));
        }
    }
    float t1[TW][Rr];
#pragma unroll
    for (int k = 0; k < TW; ++k)
#pragma unroll
        for (int r = 0; r < Rr; ++r) t1[k][r] = wave_allreduce(p[k][r]);
    SYNC();
#pragma unroll
    for (int i = 0; i < 4; ++i) {
        const int o = (i * NT + t) * 16;
        stage16(b2e + swz(o), (char*)s_a1 + (i * NT + wave * 64) * 16);
    }
    float q[TW][Rr];
#pragma unroll
    for (int k = 0; k < TW; ++k)
#pragma unroll
        for (int r = 0; r < Rr; ++r) q[k][r] = 0.f;
#pragma unroll
    for (int kc = 0; kc < NCHUNK; ++kc) {
        if (kc < 2)      { WAITVM(6); }
        else if (kc < 7) { WAITVM(2); }
        else             { WAITVM(0); }
        SYNC();
        if (kc + 2 < NCHUNK) {
            const int nb = (kc + 2) % 3;
            const int hb = (kc + 2) * HC;
            stage16(b1e + (size_t)hb * Rr * 4 + swz(t * 16),
                    (char*)s_b1[nb] + wave * 1024);
            stage16(a2e + wave * Hd + hb + lane * 4,
                    (char*)s_a2[nb] + wave * 1024);
        }
        const int cur = kc % 3;
        const int cc = kc * 64 + lane;
        float4 hv[TW];
#pragma unroll
        for (int k = 0; k < TW; ++k)
            hv[k] = *(const float4*)(h_pre + (size_t)tok[k] * Hd + 4 * cc);
        float sv[TW][4];
#pragma unroll
        for (int j = 0; j < 4; ++j) {
            const int o0 = lane * 128 + j * 32;
            const float4 w0 = *(const float4*)((const char*)s_b1[cur] + swz(o0));
            const float4 w1 = *(const float4*)((const char*)s_b1[cur] + swz(o0 + 16));
#pragma unroll
            for (int k = 0; k < TW; ++k) {
                const float x = (&hv[k].x)[j] + dot8(t1[k], w0, w1) * kScale;
                sv[k][j] = silu(x);
            }
        }
#pragma unroll
        for (int r = 0; r < Rr; ++r) {
            const float4 aw = *(const float4*)(s_a2[cur] + r * HC + lane * 4);
#pragma unroll
            for (int k = 0; k < TW; ++k)
                q[k][r] = fmaf(sv[k][0], aw.x, fmaf(sv[k][1], aw.y,
                          fmaf(sv[k][2], aw.z, fmaf(sv[k][3], aw.w, q[k][r]))));
        }
    }
    float t2[TW][Rr];
#pragma unroll
    for (int k = 0; k < TW; ++k)
#pragma unroll
        for (int r = 0; r < Rr; ++r) t2[k][r] = wave_allreduce(q[k][r]) * kScale;
    WAITVM(0); SYNC();
#pragma unroll
    for (int i = 0; i < 4; ++i) {
        const int c = lane + i * 64;
        float4 ov[TW];
#pragma unroll
        for (int k = 0; k < TW; ++k)
            ov[k] = *(const float4*)(out_pre + (size_t)tok[k] * Zd + 4 * c);
        float4 res[TW];
#pragma unroll
        for (int j = 0; j < 4; ++j) {
            const int o0 = c * 128 + j * 32;
            const float4 w0 = *(const float4*)((const char*)s_a1 + swz(o0));
            const float4 w1 = *(const float4*)((const char*)s_a1 + swz(o0 + 16));
#pragma unroll
            for (int k = 0; k < TW; ++k)
                (&res[k].x)[j] = (&ov[k].x)[j] + dot8(t2[k], w0, w1);
        }
#pragma unroll
        for (int k = 0; k < TW; ++k)
            if (val[k]) *(float4*)(out + (size_t)tok[k] * Zd + 4 * c) = res[k];
    }
}

extern "C" void kernel_launch(void* const* d_in, const int* in_sizes, int n_in,
                              void* d_out, int out_size, void* d_ws, size_t ws_size,
                              hipStream_t stream) {
    const float* z       = (const float*)d_in[0];
    const int*   a_idx   = (const int*)d_in[1];
    const float* h_pre   = (const float*)d_in[2];
    const float* out_pre = (const float*)d_in[3];
    const float* a1      = (const float*)d_in[4];
    const float* b1      = (const float*)d_in[5];
    const float* a2      = (const float*)d_in[6];
    const float* b2      = (const float*)d_in[7];
    float* out = (float*)d_out;

    const int N = in_sizes[1];  // a_idx count

    bucket_kernel<<<1, 1024, 0, stream>>>(a_idx, N, (int*)d_ws);

    int nwg = N / TB + Wn;              // 576 blocks (incl. per-expert tails)
    nwg = (nwg + 7) & ~7;               // multiple of 8 for XCD swizzle

    if (ws_size >= WS_NEEDED) {
        unsigned* wb = (unsigned*)((char*)d_ws + WOFF);
        convert_bf16<<<1536, 256, 0, stream>>>(a1, b1, a2, b2, wb);
        lora_main_bf16<<<nwg, NT, 0, stream>>>(z, h_pre, out_pre, out,
                                               (const int*)d_ws, N,
                                               (const char*)wb);
    } else {
        lora_main_f32<<<nwg, NT, 0, stream>>>(z, h_pre, out_pre,
                                              a1, b1, a2, b2, out,
                                              (const int*)d_ws, N);
    }
}